// Round 8
// baseline (138.455 us; speedup 1.0000x reference)
//
#include <hip/hip_runtime.h>
#include <hip/hip_bf16.h>

typedef __attribute__((ext_vector_type(8))) short bf16x8;
typedef __attribute__((ext_vector_type(4))) float f32x4;
typedef __attribute__((ext_vector_type(16))) float f32x16;
typedef __attribute__((ext_vector_type(4))) unsigned short u16x4;
typedef __attribute__((ext_vector_type(8))) unsigned short u16x8v;

#define S_LEN 2048
#define NHEAD 16
#define HDIM 64
#define DIM 1024

__device__ __forceinline__ unsigned short f2bf(float f) {
    union { float f; unsigned u; } x; x.f = f;
    unsigned r = x.u + 0x7FFFu + ((x.u >> 16) & 1u);
    return (unsigned short)(r >> 16);
}
__device__ __forceinline__ unsigned short f2bf_fast(float f) {
    union { float f; unsigned u; } x; x.f = f;
    return (unsigned short)((x.u + 0x8000u) >> 16);
}

__device__ __forceinline__ f32x4 mfma16(bf16x8 a, bf16x8 b, f32x4 c) {
    return __builtin_amdgcn_mfma_f32_16x16x32_bf16(a, b, c, 0, 0, 0);
}
__device__ __forceinline__ f32x16 mfma32(bf16x8 a, bf16x8 b, f32x16 c) {
    return __builtin_amdgcn_mfma_f32_32x32x16_bf16(a, b, c, 0, 0, 0);
}

__device__ __forceinline__ float fexp2(float x) {
#if __has_builtin(__builtin_amdgcn_exp2f)
    return __builtin_amdgcn_exp2f(x);
#else
    return exp2f(x);
#endif
}

__device__ __forceinline__ void gl_lds16(const void* g, void* l) {
    __builtin_amdgcn_global_load_lds(
        (const __attribute__((address_space(1))) unsigned int*)g,
        (__attribute__((address_space(3))) unsigned int*)l, 16, 0, 0);
}

// ---------- x fp32 -> bf16 ----------
__global__ __launch_bounds__(256) void xconv_kernel(const float* __restrict__ X,
                                                    unsigned short* __restrict__ Xb) {
    size_t i = ((size_t)blockIdx.x * 256 + threadIdx.x) * 8;
    float4 a = *reinterpret_cast<const float4*>(&X[i]);
    float4 b = *reinterpret_cast<const float4*>(&X[i + 4]);
    u16x8v o;
    o[0] = f2bf(a.x); o[1] = f2bf(a.y); o[2] = f2bf(a.z); o[3] = f2bf(a.w);
    o[4] = f2bf(b.x); o[5] = f2bf(b.y); o[6] = f2bf(b.z); o[7] = f2bf(b.w);
    *reinterpret_cast<u16x8v*>(&Xb[i]) = o;
}

// ---------- weight transpose + bf16 convert: W[K][N] -> Wt[N][K] ----------
__global__ __launch_bounds__(256) void wtrans_kernel(const float* __restrict__ W,
                                                     unsigned short* __restrict__ Wt,
                                                     int K, int N) {
    __shared__ float lds[64][65];
    int k0 = blockIdx.x * 64, n0 = blockIdx.y * 64;
    int tid = threadIdx.x;
    for (int idx = tid; idx < 1024; idx += 256) {
        int row = idx >> 4, c = (idx & 15) << 2;
        float4 v = *reinterpret_cast<const float4*>(&W[(size_t)(k0 + row) * N + n0 + c]);
        lds[row][c] = v.x; lds[row][c + 1] = v.y; lds[row][c + 2] = v.z; lds[row][c + 3] = v.w;
    }
    __syncthreads();
    for (int idx = tid; idx < 1024; idx += 256) {
        int row = idx >> 4, c = (idx & 15) << 2;
        u16x4 o;
        o[0] = f2bf(lds[c][row]);     o[1] = f2bf(lds[c + 1][row]);
        o[2] = f2bf(lds[c + 2][row]); o[3] = f2bf(lds[c + 3][row]);
        *reinterpret_cast<u16x4*>(&Wt[(size_t)(n0 + row) * K + k0 + c]) = o;
    }
}

// ---------- GEMM (m97 structure), unchanged ----------
template <int MODE>
__global__ __launch_bounds__(256) void gemm_kernel(
    const unsigned short* __restrict__ Ab, const unsigned short* __restrict__ Bt,
    const float* __restrict__ bias,
    unsigned short* __restrict__ Qb, unsigned short* __restrict__ Kb,
    unsigned short* __restrict__ Vt, float* __restrict__ outf) {
    __shared__ unsigned short Alds[128 * 64];
    __shared__ unsigned short Blds[128 * 64];
    const int tid = threadIdx.x;
    const int m0 = blockIdx.x * 128, n0 = blockIdx.y * 128;
    const int wid = tid >> 6, lane = tid & 63;
    const int wm = wid >> 1, wn = wid & 1;
    const int lr = lane & 15, lg = lane >> 4;

    const char* Abase = (const char*)(Ab + (size_t)m0 * 1024);
    const char* Bbase = (const char*)(Bt + (size_t)n0 * 1024);

    int srcOff[4], dstOff[4];
#pragma unroll
    for (int i = 0; i < 4; ++i) {
        int off = i * 4096 + wid * 1024 + lane * 16;
        int row = off >> 7, col = off & 127;
        srcOff[i] = row * 2048 + (col ^ ((row & 7) << 4));
        dstOff[i] = off;
    }
    const int swz = (lr & 7) << 4;

    f32x4 acc[4][4] = {};

    for (int kt = 0; kt < 16; ++kt) {
        __syncthreads();
#pragma unroll
        for (int i = 0; i < 4; ++i) {
            gl_lds16(Abase + srcOff[i] + kt * 128, (char*)Alds + dstOff[i]);
            gl_lds16(Bbase + srcOff[i] + kt * 128, (char*)Blds + dstOff[i]);
        }
        __syncthreads();

#pragma unroll
        for (int ks = 0; ks < 2; ++ks) {
            bf16x8 af[4], bfr[4];
#pragma unroll
            for (int i = 0; i < 4; ++i)
                af[i] = *reinterpret_cast<const bf16x8*>(
                    (const char*)Alds + (wm * 64 + i * 16 + lr) * 128 + ((ks * 64 + lg * 16) ^ swz));
#pragma unroll
            for (int j = 0; j < 4; ++j)
                bfr[j] = *reinterpret_cast<const bf16x8*>(
                    (const char*)Blds + (wn * 64 + j * 16 + lr) * 128 + ((ks * 64 + lg * 16) ^ swz));
            __builtin_amdgcn_s_setprio(1);
#pragma unroll
            for (int i = 0; i < 4; ++i)
#pragma unroll
                for (int j = 0; j < 4; ++j)
                    acc[i][j] = mfma16(af[i], bfr[j], acc[i][j]);
            __builtin_amdgcn_s_setprio(0);
        }
    }

    if constexpr (MODE == 0) {
        const int sec = n0 >> 10;
#pragma unroll
        for (int j = 0; j < 4; ++j) {
            int gn = n0 + wn * 64 + j * 16 + lr;
            float bv = bias[gn];
            int nn = gn & 1023, h = nn >> 6, d = nn & 63;
#pragma unroll
            for (int i = 0; i < 4; ++i) {
#pragma unroll
                for (int r = 0; r < 4; ++r) {
                    int m = m0 + wm * 64 + i * 16 + lg * 4 + r;
                    int b_ = m >> 11, s_ = m & 2047;
                    size_t bh = (size_t)(b_ * NHEAD + h);
                    float v = acc[i][j][r] + bv;
                    if (sec == 0)
                        Qb[(bh * S_LEN + s_) * HDIM + d] = f2bf(v * 0.18033688f);  // 1/8 * log2(e)
                    else if (sec == 1)
                        Kb[(bh * S_LEN + s_) * HDIM + d] = f2bf(v);
                    else
                        Vt[(bh * HDIM + d) * S_LEN + s_] = f2bf(v);
                }
            }
        }
    } else {
#pragma unroll
        for (int j = 0; j < 4; ++j) {
            int gn = n0 + wn * 64 + j * 16 + lr;
            float bv = bias[gn];
#pragma unroll
            for (int i = 0; i < 4; ++i) {
#pragma unroll
                for (int r = 0; r < 4; ++r) {
                    int m = m0 + wm * 64 + i * 16 + lg * 4 + r;
                    outf[(size_t)m * DIM + gn] = acc[i][j][r] + bv;
                }
            }
        }
    }
}

// ---------- flash attention: 4 waves x 64 q-rows, fragment-linear LDS ----------
// K/V tiles stored in MFMA-fragment order: chunk (ct|dt, kst) of 1KB holds the
// 64 lanes' 16B fragments contiguously -> ds_read = base + lane*16 + imm,
// conflict-free. Staging pre-permutes the per-lane GLOBAL source instead.
#define NT (S_LEN / 64)
__global__ __launch_bounds__(256) void attn_kernel(const unsigned short* __restrict__ Qb,
                                                   const unsigned short* __restrict__ Kb,
                                                   const unsigned short* __restrict__ Vt,
                                                   unsigned short* __restrict__ Ob) {
    __shared__ unsigned short Klds[2][64 * 64];   // 8 chunks x 1KB, fragment order
    __shared__ unsigned short Vlds[2][64 * 64];
    const int L = blockIdx.x;
    const int xcd = L & 7, slot = L >> 3;
    const int bh = xcd + 8 * (slot & 3);          // 4 heads per XCD -> K/V L2-resident
    const int qblk = slot >> 2;
    const int wid = threadIdx.x >> 6;
    const int lane = threadIdx.x & 63;
    const int l31 = lane & 31, hi = lane >> 5;
    const int q0 = qblk * 256 + wid * 64;

    // Q fragments for the two 32-row sub-tiles (scale*log2e folded upstream)
    const unsigned short* qrA = &Qb[((size_t)bh * S_LEN + q0 + l31) * HDIM];
    bf16x8 qfA[4], qfB[4];
#pragma unroll
    for (int kst = 0; kst < 4; ++kst) {
        qfA[kst] = *reinterpret_cast<const bf16x8*>(&qrA[kst * 16 + hi * 8]);
        qfB[kst] = *reinterpret_cast<const bf16x8*>(&qrA[32 * HDIM + kst * 16 + hi * 8]);
    }

    const char* kT = (const char*)&Kb[(size_t)bh * S_LEN * HDIM];  // tile jt at +jt*8192
    const char* vT = (const char*)&Vt[(size_t)bh * HDIM * S_LEN];  // tile jt at +jt*128

    // staging: wave w stages chunks 2w, 2w+1 of K and of V.
    // chunk c = (ct<<2)|kst; global src for consuming lane (l31,hi):
    //   K: (ct*32+l31)*128 + kst*32 + hi*16      V: (dt*32+l31)*4096 + kst*32 + hi*16
    const int c0 = 2 * wid, c1 = 2 * wid + 1;
    const int ks0 = ((c0 >> 2) * 32 + l31) * 128 + (c0 & 3) * 32 + hi * 16;
    const int ks1 = ((c1 >> 2) * 32 + l31) * 128 + (c1 & 3) * 32 + hi * 16;
    const int vs0 = ((c0 >> 2) * 32 + l31) * 4096 + (c0 & 3) * 32 + hi * 16;
    const int vs1 = ((c1 >> 2) * 32 + l31) * 4096 + (c1 & 3) * 32 + hi * 16;
    const int du0 = c0 * 1024, du1 = c1 * 1024;   // wave-uniform LDS byte offsets

    float lsA = 0.f, lsB = 0.f;
    f32x16 accA[2] = {}, accB[2] = {};

    // prologue: stage tile 0 -> buf 0
    gl_lds16(kT + ks0, (char*)Klds[0] + du0);
    gl_lds16(kT + ks1, (char*)Klds[0] + du1);
    gl_lds16(vT + vs0, (char*)Vlds[0] + du0);
    gl_lds16(vT + vs1, (char*)Vlds[0] + du1);
    __syncthreads();

    int cur = 0;
    for (int jt = 0; jt < NT; ++jt) {
        if (jt + 1 < NT) {
            char* kl = (char*)Klds[cur ^ 1]; char* vl = (char*)Vlds[cur ^ 1];
            size_t kof = (size_t)(jt + 1) * 8192, vof = (size_t)(jt + 1) * 128;
            gl_lds16(kT + kof + ks0, kl + du0);
            gl_lds16(kT + kof + ks1, kl + du1);
            gl_lds16(vT + vof + vs0, vl + du0);
            gl_lds16(vT + vof + vs1, vl + du1);
        }
        const char* kl = (const char*)Klds[cur] + lane * 16;
        const char* vl = (const char*)Vlds[cur] + lane * 16;

        // QK^T swapped (both sub-tiles; kb read once): lane holds q=l31,
        // keys k = 32*ct + (r&3) + 4*hi + 8*(r>>2)
        f32x16 pA0 = {}, pA1 = {}, pB0 = {}, pB1 = {};
#pragma unroll
        for (int kst = 0; kst < 4; ++kst) {
            bf16x8 kb0 = *reinterpret_cast<const bf16x8*>(kl + kst * 1024);
            bf16x8 kb1 = *reinterpret_cast<const bf16x8*>(kl + (4 + kst) * 1024);
            pA0 = mfma32(kb0, qfA[kst], pA0);
            pB0 = mfma32(kb0, qfB[kst], pB0);
            pA1 = mfma32(kb1, qfA[kst], pA1);
            pB1 = mfma32(kb1, qfB[kst], pB1);
        }

        // ---- sub A: exp + repack (runs under sub-B's MFMA chain) ----
        bf16x8 paA[4];
        {
#pragma unroll
            for (int r = 0; r < 16; ++r) {
                float e0 = fexp2(pA0[r]); pA0[r] = e0; lsA += e0;
                float e1 = fexp2(pA1[r]); pA1[r] = e1; lsA += e1;
            }
#pragma unroll
            for (int kst = 0; kst < 4; ++kst) {
                const int rb = 8 * (kst & 1);
                unsigned aw[2], bw[2];
#pragma unroll
                for (int u = 0; u < 2; ++u) {
                    unsigned a, b;
                    if (kst < 2) {
                        asm("v_cvt_pk_bf16_f32 %0, %1, %2" : "=v"(a) : "v"(pA0[rb + 2 * u]), "v"(pA0[rb + 2 * u + 1]));
                        asm("v_cvt_pk_bf16_f32 %0, %1, %2" : "=v"(b) : "v"(pA0[rb + 4 + 2 * u]), "v"(pA0[rb + 4 + 2 * u + 1]));
                    } else {
                        asm("v_cvt_pk_bf16_f32 %0, %1, %2" : "=v"(a) : "v"(pA1[rb + 2 * u]), "v"(pA1[rb + 2 * u + 1]));
                        asm("v_cvt_pk_bf16_f32 %0, %1, %2" : "=v"(b) : "v"(pA1[rb + 4 + 2 * u]), "v"(pA1[rb + 4 + 2 * u + 1]));
                    }
                    asm volatile("v_permlane32_swap_b32 %0, %1" : "+v"(a), "+v"(b));
                    aw[u] = a; bw[u] = b;
                }
                union { unsigned w[4]; bf16x8 v; } pu;
                pu.w[0] = aw[0]; pu.w[1] = aw[1]; pu.w[2] = bw[0]; pu.w[3] = bw[1];
                paA[kst] = pu.v;
            }
        }

        // ---- PV(A) (exp(B) below runs under these MFMAs) ----
#pragma unroll
        for (int kst = 0; kst < 4; ++kst) {
            bf16x8 vb0 = *reinterpret_cast<const bf16x8*>(vl + kst * 1024);
            bf16x8 vb1 = *reinterpret_cast<const bf16x8*>(vl + (4 + kst) * 1024);
            accA[0] = mfma32(paA[kst], vb0, accA[0]);
            accA[1] = mfma32(paA[kst], vb1, accA[1]);
        }

        // ---- sub B: exp + repack ----
        bf16x8 paB[4];
        {
#pragma unroll
            for (int r = 0; r < 16; ++r) {
                float e0 = fexp2(pB0[r]); pB0[r] = e0; lsB += e0;
                float e1 = fexp2(pB1[r]); pB1[r] = e1; lsB += e1;
            }
#pragma unroll
            for (int kst = 0; kst < 4; ++kst) {
                const int rb = 8 * (kst & 1);
                unsigned aw[2], bw[2];
#pragma unroll
                for (int u = 0; u < 2; ++u) {
                    unsigned a, b;
                    if (kst < 2) {
                        asm("v_cvt_pk_bf16_f32 %0, %1, %2" : "=v"(a) : "v"(pB0[rb + 2 * u]), "v"(pB0[rb + 2 * u + 1]));
                        asm("v_cvt_pk_bf16_f32 %0, %1, %2" : "=v"(b) : "v"(pB0[rb + 4 + 2 * u]), "v"(pB0[rb + 4 + 2 * u + 1]));
                    } else {
                        asm("v_cvt_pk_bf16_f32 %0, %1, %2" : "=v"(a) : "v"(pB1[rb + 2 * u]), "v"(pB1[rb + 2 * u + 1]));
                        asm("v_cvt_pk_bf16_f32 %0, %1, %2" : "=v"(b) : "v"(pB1[rb + 4 + 2 * u]), "v"(pB1[rb + 4 + 2 * u + 1]));
                    }
                    asm volatile("v_permlane32_swap_b32 %0, %1" : "+v"(a), "+v"(b));
                    aw[u] = a; bw[u] = b;
                }
                union { unsigned w[4]; bf16x8 v; } pu;
                pu.w[0] = aw[0]; pu.w[1] = aw[1]; pu.w[2] = bw[0]; pu.w[3] = bw[1];
                paB[kst] = pu.v;
            }
        }

        // ---- PV(B) (vb re-read; conflict-free and cheap) ----
#pragma unroll
        for (int kst = 0; kst < 4; ++kst) {
            bf16x8 vb0 = *reinterpret_cast<const bf16x8*>(vl + kst * 1024);
            bf16x8 vb1 = *reinterpret_cast<const bf16x8*>(vl + (4 + kst) * 1024);
            accB[0] = mfma32(paB[kst], vb0, accB[0]);
            accB[1] = mfma32(paB[kst], vb1, accB[1]);
        }

        __syncthreads();   // drains prefetch (vmcnt) + protects buf reuse
        cur ^= 1;
    }

    lsA += __shfl_xor(lsA, 32, 64);
    lsB += __shfl_xor(lsB, 32, 64);

    const int b_ = bh >> 4, h = bh & 15;
#pragma unroll
    for (int dt = 0; dt < 2; ++dt)
#pragma unroll
        for (int r = 0; r < 16; ++r) {
            int rq = (r & 3) + 8 * (r >> 2) + 4 * hi;
            float oA = accA[dt][r] / __shfl(lsA, rq, 64);
            float oB = accB[dt][r] / __shfl(lsB, rq, 64);
            int qA = q0 + rq, qB = q0 + 32 + rq;
            Ob[((size_t)(b_ * S_LEN + qA)) * DIM + h * HDIM + dt * 32 + l31] = f2bf_fast(oA);
            Ob[((size_t)(b_ * S_LEN + qB)) * DIM + h * HDIM + dt * 32 + l31] = f2bf_fast(oB);
        }
}

extern "C" void kernel_launch(void* const* d_in, const int* in_sizes, int n_in,
                              void* d_out, int out_size, void* d_ws, size_t ws_size,
                              hipStream_t stream) {
    const float* x      = (const float*)d_in[0];
    const float* qkv_w  = (const float*)d_in[1];
    const float* qkv_b  = (const float*)d_in[2];
    const float* proj_w = (const float*)d_in[3];
    const float* proj_b = (const float*)d_in[4];
    float* out = (float*)d_out;

    unsigned short* Wqkvt = (unsigned short*)d_ws;         // [3072][1024] bf16
    unsigned short* Wpt   = Wqkvt + 3072 * 1024;           // [1024][1024] bf16
    unsigned short* Qb    = Wpt + 1024 * 1024;             // [32][2048][64] bf16 (scale*log2e folded)
    unsigned short* Kb    = Qb + 32 * 2048 * 64;           // [32][2048][64]
    unsigned short* Vt    = Kb + 32 * 2048 * 64;           // [32][64][2048]
    unsigned short* Ob    = Vt + 32 * 2048 * 64;           // [4096][1024] bf16
    unsigned short* Xb    = Ob + 4096 * 1024;              // [4096][1024] bf16

    xconv_kernel<<<2048, 256, 0, stream>>>(x, Xb);
    wtrans_kernel<<<dim3(16, 48), 256, 0, stream>>>(qkv_w, Wqkvt, 1024, 3072);
    wtrans_kernel<<<dim3(16, 16), 256, 0, stream>>>(proj_w, Wpt, 1024, 1024);

    gemm_kernel<0><<<dim3(32, 24), 256, 0, stream>>>(Xb, Wqkvt, qkv_b, Qb, Kb, Vt, nullptr);
    attn_kernel<<<256, 256, 0, stream>>>(Qb, Kb, Vt, Ob);
    gemm_kernel<1><<<dim3(32, 8), 256, 0, stream>>>(Ob, Wpt, proj_b, nullptr, nullptr, nullptr, out);
}

// Round 9
// 121.879 us; speedup vs baseline: 1.1360x; 1.1360x over previous
//
#include <hip/hip_runtime.h>
#include <hip/hip_bf16.h>

typedef __attribute__((ext_vector_type(8))) short bf16x8;
typedef __attribute__((ext_vector_type(4))) float f32x4;
typedef __attribute__((ext_vector_type(16))) float f32x16;
typedef __attribute__((ext_vector_type(4))) unsigned short u16x4;
typedef __attribute__((ext_vector_type(8))) unsigned short u16x8v;

#define S_LEN 2048
#define NHEAD 16
#define HDIM 64
#define DIM 1024

__device__ __forceinline__ unsigned short f2bf(float f) {
    union { float f; unsigned u; } x; x.f = f;
    unsigned r = x.u + 0x7FFFu + ((x.u >> 16) & 1u);
    return (unsigned short)(r >> 16);
}
__device__ __forceinline__ unsigned short f2bf_fast(float f) {
    union { float f; unsigned u; } x; x.f = f;
    return (unsigned short)((x.u + 0x8000u) >> 16);
}

__device__ __forceinline__ f32x4 mfma16(bf16x8 a, bf16x8 b, f32x4 c) {
    return __builtin_amdgcn_mfma_f32_16x16x32_bf16(a, b, c, 0, 0, 0);
}
__device__ __forceinline__ f32x16 mfma32(bf16x8 a, bf16x8 b, f32x16 c) {
    return __builtin_amdgcn_mfma_f32_32x32x16_bf16(a, b, c, 0, 0, 0);
}

__device__ __forceinline__ float fexp2(float x) {
#if __has_builtin(__builtin_amdgcn_exp2f)
    return __builtin_amdgcn_exp2f(x);
#else
    return exp2f(x);
#endif
}

__device__ __forceinline__ void gl_lds16(const void* g, void* l) {
    __builtin_amdgcn_global_load_lds(
        (const __attribute__((address_space(1))) unsigned int*)g,
        (__attribute__((address_space(3))) unsigned int*)l, 16, 0, 0);
}

// ---------- x fp32 -> bf16 ----------
__global__ __launch_bounds__(256) void xconv_kernel(const float* __restrict__ X,
                                                    unsigned short* __restrict__ Xb) {
    size_t i = ((size_t)blockIdx.x * 256 + threadIdx.x) * 8;
    float4 a = *reinterpret_cast<const float4*>(&X[i]);
    float4 b = *reinterpret_cast<const float4*>(&X[i + 4]);
    u16x8v o;
    o[0] = f2bf(a.x); o[1] = f2bf(a.y); o[2] = f2bf(a.z); o[3] = f2bf(a.w);
    o[4] = f2bf(b.x); o[5] = f2bf(b.y); o[6] = f2bf(b.z); o[7] = f2bf(b.w);
    *reinterpret_cast<u16x8v*>(&Xb[i]) = o;
}

// ---------- weight transpose + bf16 convert: W[K][N] -> Wt[N][K] ----------
__global__ __launch_bounds__(256) void wtrans_kernel(const float* __restrict__ W,
                                                     unsigned short* __restrict__ Wt,
                                                     int K, int N) {
    __shared__ float lds[64][65];
    int k0 = blockIdx.x * 64, n0 = blockIdx.y * 64;
    int tid = threadIdx.x;
    for (int idx = tid; idx < 1024; idx += 256) {
        int row = idx >> 4, c = (idx & 15) << 2;
        float4 v = *reinterpret_cast<const float4*>(&W[(size_t)(k0 + row) * N + n0 + c]);
        lds[row][c] = v.x; lds[row][c + 1] = v.y; lds[row][c + 2] = v.z; lds[row][c + 3] = v.w;
    }
    __syncthreads();
    for (int idx = tid; idx < 1024; idx += 256) {
        int row = idx >> 4, c = (idx & 15) << 2;
        u16x4 o;
        o[0] = f2bf(lds[c][row]);     o[1] = f2bf(lds[c + 1][row]);
        o[2] = f2bf(lds[c + 2][row]); o[3] = f2bf(lds[c + 3][row]);
        *reinterpret_cast<u16x4*>(&Wt[(size_t)(n0 + row) * K + k0 + c]) = o;
    }
}

// ---------- GEMM (m97 structure), unchanged ----------
template <int MODE>
__global__ __launch_bounds__(256) void gemm_kernel(
    const unsigned short* __restrict__ Ab, const unsigned short* __restrict__ Bt,
    const float* __restrict__ bias,
    unsigned short* __restrict__ Qb, unsigned short* __restrict__ Kb,
    unsigned short* __restrict__ Vt, float* __restrict__ outf) {
    __shared__ unsigned short Alds[128 * 64];
    __shared__ unsigned short Blds[128 * 64];
    const int tid = threadIdx.x;
    const int m0 = blockIdx.x * 128, n0 = blockIdx.y * 128;
    const int wid = tid >> 6, lane = tid & 63;
    const int wm = wid >> 1, wn = wid & 1;
    const int lr = lane & 15, lg = lane >> 4;

    const char* Abase = (const char*)(Ab + (size_t)m0 * 1024);
    const char* Bbase = (const char*)(Bt + (size_t)n0 * 1024);

    int srcOff[4], dstOff[4];
#pragma unroll
    for (int i = 0; i < 4; ++i) {
        int off = i * 4096 + wid * 1024 + lane * 16;
        int row = off >> 7, col = off & 127;
        srcOff[i] = row * 2048 + (col ^ ((row & 7) << 4));
        dstOff[i] = off;
    }
    const int swz = (lr & 7) << 4;

    f32x4 acc[4][4] = {};

    for (int kt = 0; kt < 16; ++kt) {
        __syncthreads();
#pragma unroll
        for (int i = 0; i < 4; ++i) {
            gl_lds16(Abase + srcOff[i] + kt * 128, (char*)Alds + dstOff[i]);
            gl_lds16(Bbase + srcOff[i] + kt * 128, (char*)Blds + dstOff[i]);
        }
        __syncthreads();

#pragma unroll
        for (int ks = 0; ks < 2; ++ks) {
            bf16x8 af[4], bfr[4];
#pragma unroll
            for (int i = 0; i < 4; ++i)
                af[i] = *reinterpret_cast<const bf16x8*>(
                    (const char*)Alds + (wm * 64 + i * 16 + lr) * 128 + ((ks * 64 + lg * 16) ^ swz));
#pragma unroll
            for (int j = 0; j < 4; ++j)
                bfr[j] = *reinterpret_cast<const bf16x8*>(
                    (const char*)Blds + (wn * 64 + j * 16 + lr) * 128 + ((ks * 64 + lg * 16) ^ swz));
            __builtin_amdgcn_s_setprio(1);
#pragma unroll
            for (int i = 0; i < 4; ++i)
#pragma unroll
                for (int j = 0; j < 4; ++j)
                    acc[i][j] = mfma16(af[i], bfr[j], acc[i][j]);
            __builtin_amdgcn_s_setprio(0);
        }
    }

    if constexpr (MODE == 0) {
        const int sec = n0 >> 10;
#pragma unroll
        for (int j = 0; j < 4; ++j) {
            int gn = n0 + wn * 64 + j * 16 + lr;
            float bv = bias[gn];
            int nn = gn & 1023, h = nn >> 6, d = nn & 63;
#pragma unroll
            for (int i = 0; i < 4; ++i) {
#pragma unroll
                for (int r = 0; r < 4; ++r) {
                    int m = m0 + wm * 64 + i * 16 + lg * 4 + r;
                    int b_ = m >> 11, s_ = m & 2047;
                    size_t bh = (size_t)(b_ * NHEAD + h);
                    float v = acc[i][j][r] + bv;
                    if (sec == 0)
                        Qb[(bh * S_LEN + s_) * HDIM + d] = f2bf(v * 0.18033688f);  // 1/8 * log2(e)
                    else if (sec == 1)
                        Kb[(bh * S_LEN + s_) * HDIM + d] = f2bf(v);
                    else
                        Vt[(bh * HDIM + d) * S_LEN + s_] = f2bf(v);
                }
            }
        }
    } else {
#pragma unroll
        for (int j = 0; j < 4; ++j) {
            int gn = n0 + wn * 64 + j * 16 + lr;
            float bv = bias[gn];
#pragma unroll
            for (int i = 0; i < 4; ++i) {
#pragma unroll
                for (int r = 0; r < 4; ++r) {
                    int m = m0 + wm * 64 + i * 16 + lg * 4 + r;
                    outf[(size_t)m * DIM + gn] = acc[i][j][r] + bv;
                }
            }
        }
    }
}

// ---------- flash attention: 4 waves x 32 q-rows, fragment-linear LDS, XCD swizzle ----------
// K/V tiles in MFMA-fragment order (chunk (ct|dt,kst) = 1KB of 64 lanes' 16B frags):
// ds_read = base + lane*16 + imm -> conflict-free, zero addr VALU (verified R8).
// Topology restored to R7's 2 blocks/CU (2 waves/SIMD) for TLP (R8 lesson).
#define NT (S_LEN / 64)
__global__ __launch_bounds__(256) void attn_kernel(const unsigned short* __restrict__ Qb,
                                                   const unsigned short* __restrict__ Kb,
                                                   const unsigned short* __restrict__ Vt,
                                                   unsigned short* __restrict__ Ob) {
    __shared__ unsigned short Klds[2][64 * 64];   // 8 chunks x 1KB, fragment order
    __shared__ unsigned short Vlds[2][64 * 64];
    const int L = blockIdx.x;                     // 0..511
    const int xcd = L & 7, slot = L >> 3;         // 64 slots per XCD
    const int bh = xcd + 8 * (slot & 3);          // 4 heads per XCD -> K/V L2-resident
    const int qblk = slot >> 2;                   // 0..15
    const int wid = threadIdx.x >> 6;
    const int lane = threadIdx.x & 63;
    const int l31 = lane & 31, hi = lane >> 5;
    const int q0 = qblk * 128 + wid * 32;

    // Q fragments (scale*log2e folded upstream): frag[q=l31][feat=kst*16+hi*8+j]
    const unsigned short* qrow = &Qb[((size_t)bh * S_LEN + q0 + l31) * HDIM];
    bf16x8 qf[4];
#pragma unroll
    for (int kst = 0; kst < 4; ++kst)
        qf[kst] = *reinterpret_cast<const bf16x8*>(&qrow[kst * 16 + hi * 8]);

    const char* kT = (const char*)&Kb[(size_t)bh * S_LEN * HDIM];  // tile jt at +jt*8192
    const char* vT = (const char*)&Vt[(size_t)bh * HDIM * S_LEN];  // tile jt at +jt*128

    // staging: wave w stages chunks 2w, 2w+1 of K and of V (8 chunks each total).
    // chunk c = (ct<<2)|kst; source for slot-lane (l31,hi):
    //   K: (ct*32+l31)*128 + kst*32 + hi*16     V: (dt*32+l31)*4096 + kst*32 + hi*16
    const int c0 = 2 * wid, c1 = 2 * wid + 1;
    const int ks0 = ((c0 >> 2) * 32 + l31) * 128 + (c0 & 3) * 32 + hi * 16;
    const int ks1 = ((c1 >> 2) * 32 + l31) * 128 + (c1 & 3) * 32 + hi * 16;
    const int vs0 = ((c0 >> 2) * 32 + l31) * 4096 + (c0 & 3) * 32 + hi * 16;
    const int vs1 = ((c1 >> 2) * 32 + l31) * 4096 + (c1 & 3) * 32 + hi * 16;
    const int du0 = c0 * 1024, du1 = c1 * 1024;   // wave-uniform LDS byte offsets

    float ls = 0.f;                                // per-lane partial row-sum (q = l31)
    f32x16 acc[2] = {};

    // prologue: stage tile 0 -> buf 0
    gl_lds16(kT + ks0, (char*)Klds[0] + du0);
    gl_lds16(kT + ks1, (char*)Klds[0] + du1);
    gl_lds16(vT + vs0, (char*)Vlds[0] + du0);
    gl_lds16(vT + vs1, (char*)Vlds[0] + du1);
    __syncthreads();

    int cur = 0;
    for (int jt = 0; jt < NT; ++jt) {
        if (jt + 1 < NT) {
            char* kl = (char*)Klds[cur ^ 1]; char* vl = (char*)Vlds[cur ^ 1];
            size_t kof = (size_t)(jt + 1) * 8192, vof = (size_t)(jt + 1) * 128;
            gl_lds16(kT + kof + ks0, kl + du0);
            gl_lds16(kT + kof + ks1, kl + du1);
            gl_lds16(vT + vof + vs0, vl + du0);
            gl_lds16(vT + vof + vs1, vl + du1);
        }
        const char* kl = (const char*)Klds[cur] + lane * 16;
        const char* vl = (const char*)Vlds[cur] + lane * 16;

        // QK^T swapped: lane holds q = l31, keys k = 32*ct + (r&3) + 4*hi + 8*(r>>2)
        f32x16 p[2] = {};
        __builtin_amdgcn_s_setprio(1);
#pragma unroll
        for (int ct = 0; ct < 2; ++ct)
#pragma unroll
            for (int kst = 0; kst < 4; ++kst) {
                bf16x8 kb = *reinterpret_cast<const bf16x8*>(kl + (ct * 4 + kst) * 1024);
                p[ct] = mfma32(kb, qf[kst], p[ct]);
            }
        __builtin_amdgcn_s_setprio(0);

        // P = exp2(s) in-place; per-lane sum only (no cross-lane work per tile)
#pragma unroll
        for (int ct = 0; ct < 2; ++ct)
#pragma unroll
            for (int r = 0; r < 16; ++r) {
                float e = fexp2(p[ct][r]);
                p[ct][r] = e;
                ls += e;
            }

        // Redistribute P -> PV A-frags: pa[kst] = P[q=l31][k=kst*16+hi*8+j]
        bf16x8 pa[4];
#pragma unroll
        for (int kst = 0; kst < 4; ++kst) {
            const int ctq = kst >> 1, rb = 8 * (kst & 1);
            unsigned aw[2], bw[2];
#pragma unroll
            for (int u = 0; u < 2; ++u) {
                unsigned a, b;
                asm("v_cvt_pk_bf16_f32 %0, %1, %2"
                    : "=v"(a) : "v"(p[ctq][rb + 2 * u]), "v"(p[ctq][rb + 2 * u + 1]));
                asm("v_cvt_pk_bf16_f32 %0, %1, %2"
                    : "=v"(b) : "v"(p[ctq][rb + 4 + 2 * u]), "v"(p[ctq][rb + 4 + 2 * u + 1]));
                asm volatile("v_permlane32_swap_b32 %0, %1" : "+v"(a), "+v"(b));
                aw[u] = a; bw[u] = b;
            }
            union { unsigned w[4]; bf16x8 v; } pu;
            pu.w[0] = aw[0]; pu.w[1] = aw[1]; pu.w[2] = bw[0]; pu.w[3] = bw[1];
            pa[kst] = pu.v;
        }

        // PV: A = P[q rows], B = V[d cols]
        __builtin_amdgcn_s_setprio(1);
#pragma unroll
        for (int dt = 0; dt < 2; ++dt)
#pragma unroll
            for (int kst = 0; kst < 4; ++kst) {
                bf16x8 vb = *reinterpret_cast<const bf16x8*>(vl + (dt * 4 + kst) * 1024);
                acc[dt] = mfma32(pa[kst], vb, acc[dt]);
            }
        __builtin_amdgcn_s_setprio(0);

        __syncthreads();   // drains prefetch (vmcnt) + protects buf reuse
        cur ^= 1;
    }

    // partner lane holds the other half of q = l31's keys
    ls += __shfl_xor(ls, 32, 64);

    float inv[16];
#pragma unroll
    for (int r = 0; r < 16; ++r) {
        int rq = (r & 3) + 8 * (r >> 2) + 4 * hi;
        inv[r] = 1.f / __shfl(ls, rq, 64);
    }

    const int b_ = bh >> 4, h = bh & 15;
#pragma unroll
    for (int dt = 0; dt < 2; ++dt)
#pragma unroll
        for (int r = 0; r < 16; ++r) {
            int rq = (r & 3) + 8 * (r >> 2) + 4 * hi;
            float o = acc[dt][r] * inv[r];
            int q = q0 + rq;
            Ob[((size_t)(b_ * S_LEN + q)) * DIM + h * HDIM + dt * 32 + l31] = f2bf_fast(o);
        }
}

extern "C" void kernel_launch(void* const* d_in, const int* in_sizes, int n_in,
                              void* d_out, int out_size, void* d_ws, size_t ws_size,
                              hipStream_t stream) {
    const float* x      = (const float*)d_in[0];
    const float* qkv_w  = (const float*)d_in[1];
    const float* qkv_b  = (const float*)d_in[2];
    const float* proj_w = (const float*)d_in[3];
    const float* proj_b = (const float*)d_in[4];
    float* out = (float*)d_out;

    unsigned short* Wqkvt = (unsigned short*)d_ws;         // [3072][1024] bf16
    unsigned short* Wpt   = Wqkvt + 3072 * 1024;           // [1024][1024] bf16
    unsigned short* Qb    = Wpt + 1024 * 1024;             // [32][2048][64] bf16 (scale*log2e folded)
    unsigned short* Kb    = Qb + 32 * 2048 * 64;           // [32][2048][64]
    unsigned short* Vt    = Kb + 32 * 2048 * 64;           // [32][64][2048]
    unsigned short* Ob    = Vt + 32 * 2048 * 64;           // [4096][1024] bf16
    unsigned short* Xb    = Ob + 4096 * 1024;              // [4096][1024] bf16

    xconv_kernel<<<2048, 256, 0, stream>>>(x, Xb);
    wtrans_kernel<<<dim3(16, 48), 256, 0, stream>>>(qkv_w, Wqkvt, 1024, 3072);
    wtrans_kernel<<<dim3(16, 16), 256, 0, stream>>>(proj_w, Wpt, 1024, 1024);

    gemm_kernel<0><<<dim3(32, 24), 256, 0, stream>>>(Xb, Wqkvt, qkv_b, Qb, Kb, Vt, nullptr);
    attn_kernel<<<512, 256, 0, stream>>>(Qb, Kb, Vt, Ob);
    gemm_kernel<1><<<dim3(32, 8), 256, 0, stream>>>(Ob, Wpt, proj_b, nullptr, nullptr, nullptr, out);
}